// Round 6
// baseline (611.895 us; speedup 1.0000x reference)
//
#include <hip/hip_runtime.h>
#include <math.h>

#define NN 20000
#define NE 320000
#define IN_DIM 16
#define HID 64
#define HEADS 4
#define HD 256          // HEADS*HID
#define OUTW 208        // 16 + 3*64
#define NEG 0.2f

typedef unsigned short u16;
typedef unsigned int u32;
typedef __attribute__((ext_vector_type(8))) short bf16x8;   // MFMA A/B frag
typedef __attribute__((ext_vector_type(4))) float f32x4;    // MFMA C/D frag

__device__ __forceinline__ float b2f(u16 u) {
  union { u32 i; float f; } c; c.i = ((u32)u) << 16; return c.f;
}
__device__ __forceinline__ u16 f2b(float f) {
  union { float f; u32 i; } c; c.f = f;
  u32 r = (c.i + 0x7FFFu + ((c.i >> 16) & 1u)) >> 16;
  return (u16)r;
}

// ---------------- embed: feat = node_feat @ W_embed + b; also write out cols 0..79
__global__ void k_embed(const float* __restrict__ nf, const float* __restrict__ We,
                        const float* __restrict__ be, float* __restrict__ feat,
                        float* __restrict__ out) {
  int tid = blockIdx.x * blockDim.x + threadIdx.x;   // NN*64 threads
  int n = tid >> 6, c = tid & 63;
  if (n >= NN) return;
  float acc = be[c];
#pragma unroll
  for (int k = 0; k < IN_DIM; ++k)
    acc += nf[n * IN_DIM + k] * We[k * HID + c];
  feat[n * HID + c] = acc;
  out[n * OUTW + 16 + c] = acc;
  if (c < IN_DIM) out[n * OUTW + c] = nf[n * IN_DIM + c];
}

// ---------------- CSR build over dst
__global__ void k_count(const int* __restrict__ dst, int* __restrict__ counts) {
  int e = blockIdx.x * blockDim.x + threadIdx.x;
  if (e < NE) atomicAdd(&counts[dst[e]], 1);
}

// single block, 1024 threads, shuffle-based scan (3 barriers per 1024-chunk)
__global__ void k_scan(const int* __restrict__ counts, int* __restrict__ rowptr) {
  __shared__ int wsum[16];
  __shared__ int tot;
  int lane = threadIdx.x & 63, wid = threadIdx.x >> 6;
  int running = 0;
  if (threadIdx.x == 0) rowptr[0] = 0;
  for (int base = 0; base < NN; base += 1024) {
    int i = base + threadIdx.x;
    int x = (i < NN) ? counts[i] : 0;
#pragma unroll
    for (int d = 1; d < 64; d <<= 1) {
      int t = __shfl_up(x, d);
      if (lane >= d) x += t;
    }
    if (lane == 63) wsum[wid] = x;
    __syncthreads();
    if (wid == 0) {
      int wv = (lane < 16) ? wsum[lane] : 0;
#pragma unroll
      for (int d = 1; d < 16; d <<= 1) {
        int t = __shfl_up(wv, d);
        if (lane >= d) wv += t;
      }
      if (lane < 16) wsum[lane] = wv;     // inclusive wave-prefix
      if (lane == 15) tot = wv;
    }
    __syncthreads();
    int wpre = (wid == 0) ? 0 : wsum[wid - 1];
    if (i < NN) rowptr[i + 1] = running + wpre + x;
    running += tot;
    __syncthreads();   // protect wsum/tot before next chunk overwrites
  }
}

// scatter: eidx (CSR slot -> original edge), src/dst permuted into CSR order
__global__ void k_scatter(const int* __restrict__ dst, const int* __restrict__ src,
                          const int* __restrict__ rowptr, int* __restrict__ cursor,
                          int* __restrict__ eidx, int* __restrict__ srcp,
                          int* __restrict__ dstp) {
  int e = blockIdx.x * blockDim.x + threadIdx.x;
  if (e >= NE) return;
  int d = dst[e];
  int pos = rowptr[d] + atomicAdd(&cursor[d], 1);
  eidx[pos] = e;
  srcp[pos] = src[e];
  dstp[pos] = d;
}

// ---------------- coalesced f32 -> bf16 convert of edge_feat (original order)
__global__ void k_convert(const float* __restrict__ ef, u16* __restrict__ efb) {
  int t = blockIdx.x * blockDim.x + threadIdx.x;   // NE*HID/4 threads
  float4 v = *reinterpret_cast<const float4*>(&ef[(size_t)t * 4]);
  ushort4 o;
  o.x = f2b(v.x); o.y = f2b(v.y); o.z = f2b(v.z); o.w = f2b(v.w);
  *reinterpret_cast<ushort4*>(&efb[(size_t)t * 4]) = o;
}

// ---------------- transpose + bf16-convert W_fij: Wt[n][k] = Wf[k][n]
__global__ void k_prepw(const float* __restrict__ Wf, u16* __restrict__ Wt) {
  int tid = blockIdx.x * blockDim.x + threadIdx.x;   // HID*HD threads
  int n = tid >> 6, k = tid & 63;
  if (n >= HD) return;
  Wt[n * HID + k] = f2b(Wf[k * HD + n]);
}

// ---------------- node projections: fni (+b_att folded), fnj, hn -> bf16
// 16 nodes per block (halves weight re-reads vs 8)
__global__ __launch_bounds__(256) void k_nodeproj(
    const float* __restrict__ feat, const float* __restrict__ Wni,
    const float* __restrict__ Wnj, const float* __restrict__ Wnd,
    const float* __restrict__ batt, u16* __restrict__ fni,
    u16* __restrict__ fnj, u16* __restrict__ hn) {
  __shared__ float hs[16 * HID];
  int n0 = blockIdx.x * 16;
  int c = threadIdx.x;
  for (int i = threadIdx.x; i < 16 * HID; i += 256)
    hs[i] = feat[(size_t)(n0 + (i >> 6)) * HID + (i & 63)];
  __syncthreads();
  float aI[16] = {0}, aJ[16] = {0}, aN[16] = {0};
  for (int k = 0; k < HID; ++k) {
    float wi = Wni[k * HD + c], wj = Wnj[k * HD + c], wn = Wnd[k * HD + c];
#pragma unroll
    for (int t = 0; t < 16; ++t) {
      float x = hs[t * HID + k];
      aI[t] += x * wi; aJ[t] += x * wj; aN[t] += x * wn;
    }
  }
  float b = batt[c];
#pragma unroll
  for (int t = 0; t < 16; ++t) {
    int n = n0 + t;
    fni[(size_t)n * HD + c] = f2b(aI[t] + b);
    fnj[(size_t)n * HD + c] = f2b(aJ[t]);
    hn[(size_t)n * HD + c]  = f2b(aN[t]);
  }
}

// ---------------- edge logits via MFMA over CSR slots, software-pipelined
__global__ __launch_bounds__(256) void k_edgelogits(
    const u16* __restrict__ efb, const int* __restrict__ eidx,
    const int* __restrict__ srcp, const int* __restrict__ dstp,
    const u16* __restrict__ fni, const u16* __restrict__ fnj,
    const u16* __restrict__ Wt, const float* __restrict__ attnL,
    float* __restrict__ elog) {
  __shared__ float gb[HEADS][16][68];   // per-wave slice, +4 pad
  int h = threadIdx.x >> 6;            // wave = head
  int l = threadIdx.x & 63;
  int q = l >> 4;                      // quad
  int n = l & 15;
  bf16x8 bfr[4][2];
#pragma unroll
  for (int nt = 0; nt < 4; ++nt)
#pragma unroll
    for (int kk = 0; kk < 2; ++kk)
      bfr[nt][kk] = *reinterpret_cast<const bf16x8*>(
          &Wt[(h * 64 + nt * 16 + n) * HID + kk * 32 + q * 8]);
  float at[4];
#pragma unroll
  for (int nt = 0; nt < 4; ++nt) at[nt] = attnL[h * 64 + nt * 16 + n];

  const int NT = NE / 16;  // 20000 tiles
  int tile = blockIdx.x;
  ushort4 av[4], bv[4];
  bf16x8 a0 = {}, a1 = {};
  if (tile < NT) {   // prologue: prefetch first tile
    int i0 = tile * 16;
    int er = eidx[i0 + n];
    a0 = *reinterpret_cast<const bf16x8*>(&efb[(size_t)er * HID + q * 8]);
    a1 = *reinterpret_cast<const bf16x8*>(&efb[(size_t)er * HID + 32 + q * 8]);
#pragma unroll
    for (int p = 0; p < 4; ++p) {
      int i = i0 + p * 4 + q;
      int s = srcp[i], d = dstp[i];
      av[p] = *reinterpret_cast<const ushort4*>(&fni[(size_t)s * HD + h * 64 + 4 * n]);
      bv[p] = *reinterpret_cast<const ushort4*>(&fnj[(size_t)d * HD + h * 64 + 4 * n]);
    }
  }
  while (tile < NT) {
    int i0 = tile * 16;
    int nxt = tile + gridDim.x;
    // commit current tile's gathers to the wave-private LDS slice
#pragma unroll
    for (int p = 0; p < 4; ++p) {
      float4 g;
      g.x = b2f(av[p].x) + b2f(bv[p].x);
      g.y = b2f(av[p].y) + b2f(bv[p].y);
      g.z = b2f(av[p].z) + b2f(bv[p].z);
      g.w = b2f(av[p].w) + b2f(bv[p].w);
      *reinterpret_cast<float4*>(&gb[h][p * 4 + q][4 * n]) = g;
    }
    bf16x8 ca0 = a0, ca1 = a1;
    // prefetch next tile while epilogue computes
    if (nxt < NT) {
      int i0n = nxt * 16;
      int er = eidx[i0n + n];
      a0 = *reinterpret_cast<const bf16x8*>(&efb[(size_t)er * HID + q * 8]);
      a1 = *reinterpret_cast<const bf16x8*>(&efb[(size_t)er * HID + 32 + q * 8]);
#pragma unroll
      for (int p = 0; p < 4; ++p) {
        int i = i0n + p * 4 + q;
        int s = srcp[i], d = dstp[i];
        av[p] = *reinterpret_cast<const ushort4*>(&fni[(size_t)s * HD + h * 64 + 4 * n]);
        bv[p] = *reinterpret_cast<const ushort4*>(&fnj[(size_t)d * HD + h * 64 + 4 * n]);
      }
    }
    // epilogue: MFMA + lrelu + attn-dot + cross-lane reduce
    float sumr[4] = {0.f, 0.f, 0.f, 0.f};
#pragma unroll
    for (int nt = 0; nt < 4; ++nt) {
      f32x4 acc = {0.f, 0.f, 0.f, 0.f};
      acc = __builtin_amdgcn_mfma_f32_16x16x32_bf16(ca0, bfr[nt][0], acc, 0, 0, 0);
      acc = __builtin_amdgcn_mfma_f32_16x16x32_bf16(ca1, bfr[nt][1], acc, 0, 0, 0);
#pragma unroll
      for (int r = 0; r < 4; ++r) {
        float v = acc[r] + gb[h][q * 4 + r][nt * 16 + n];
        v = v > 0.f ? v : NEG * v;
        sumr[r] += v * at[nt];
      }
    }
#pragma unroll
    for (int r = 0; r < 4; ++r) {
      float v = sumr[r];
      v += __shfl_xor(v, 1);
      v += __shfl_xor(v, 2);
      v += __shfl_xor(v, 4);
      v += __shfl_xor(v, 8);
      sumr[r] = v;
    }
    if (n == 0) {
#pragma unroll
      for (int r = 0; r < 4; ++r)
        elog[(size_t)(i0 + q * 4 + r) * HEADS + h] = sumr[r];
    }
    tile = nxt;
  }
}

// ---------------- aggregation: one wave per node; softmax stats fused; unroll x8
__global__ __launch_bounds__(256) void k_agg(
    const int* __restrict__ rowptr, const int* __restrict__ srcp,
    const float* __restrict__ elog, const u16* __restrict__ hn,
    float* __restrict__ agg) {
  int n = (blockIdx.x * blockDim.x + threadIdx.x) >> 6;
  int j = threadIdx.x & 63;
  if (n >= NN) return;
  int s0 = rowptr[n], s1 = rowptr[n + 1];
  int h = j >> 4;
  // fused softmax stats over the contiguous elog row (L1/L2-resident)
  float m = -1e30f;
  for (int i = s0; i < s1; ++i) m = fmaxf(m, elog[(size_t)i * HEADS + h]);
  float z = 0.f;
  for (int i = s0; i < s1; ++i) z += __expf(elog[(size_t)i * HEADS + h] - m);
  float invz = (z > 0.f) ? 1.0f / z : 0.f;

  float4 ac[8];
#pragma unroll
  for (int t = 0; t < 8; ++t) ac[t] = make_float4(0, 0, 0, 0);
  int i = s0;
  for (; i + 8 <= s1; i += 8) {
    int sv[8]; float wv[8]; ushort4 vv[8];
#pragma unroll
    for (int t = 0; t < 8; ++t) sv[t] = srcp[i + t];
#pragma unroll
    for (int t = 0; t < 8; ++t) wv[t] = __expf(elog[(size_t)(i + t) * HEADS + h] - m) * invz;
#pragma unroll
    for (int t = 0; t < 8; ++t)
      vv[t] = *reinterpret_cast<const ushort4*>(&hn[(size_t)sv[t] * HD + 4 * j]);
#pragma unroll
    for (int t = 0; t < 8; ++t) {
      ac[t].x += b2f(vv[t].x) * wv[t]; ac[t].y += b2f(vv[t].y) * wv[t];
      ac[t].z += b2f(vv[t].z) * wv[t]; ac[t].w += b2f(vv[t].w) * wv[t];
    }
  }
  for (; i < s1; ++i) {
    int s = srcp[i];
    float w = __expf(elog[(size_t)i * HEADS + h] - m) * invz;
    ushort4 v = *reinterpret_cast<const ushort4*>(&hn[(size_t)s * HD + 4 * j]);
    ac[0].x += b2f(v.x) * w; ac[0].y += b2f(v.y) * w;
    ac[0].z += b2f(v.z) * w; ac[0].w += b2f(v.w) * w;
  }
  float4 acc;
  acc.x = ((ac[0].x + ac[1].x) + (ac[2].x + ac[3].x)) + ((ac[4].x + ac[5].x) + (ac[6].x + ac[7].x));
  acc.y = ((ac[0].y + ac[1].y) + (ac[2].y + ac[3].y)) + ((ac[4].y + ac[5].y) + (ac[6].y + ac[7].y));
  acc.z = ((ac[0].z + ac[1].z) + (ac[2].z + ac[3].z)) + ((ac[4].z + ac[5].z) + (ac[6].z + ac[7].z));
  acc.w = ((ac[0].w + ac[1].w) + (ac[2].w + ac[3].w)) + ((ac[4].w + ac[5].w) + (ac[6].w + ac[7].w));
  *reinterpret_cast<float4*>(&agg[(size_t)n * HD + 4 * j]) = acc;
}

// ---------------- MLP + residual: feat = agg @ W_mlp + b + feat; write out slice
__global__ __launch_bounds__(256) void k_mlp(
    const float* __restrict__ agg, const float* __restrict__ Wm,
    const float* __restrict__ bm, float* __restrict__ feat,
    float* __restrict__ out, int outoff) {
  __shared__ float as_[32 * HD];
  int n0 = blockIdx.x * 32;
  for (int i = threadIdx.x; i < 32 * HD; i += 256) as_[i] = agg[(size_t)n0 * HD + i];
  __syncthreads();
  int c = threadIdx.x & 63;
  int g = threadIdx.x >> 6;
  float acc[8] = {0};
  for (int k = 0; k < HD; ++k) {
    float wv = Wm[k * HID + c];
#pragma unroll
    for (int t = 0; t < 8; ++t)
      acc[t] += as_[(g * 8 + t) * HD + k] * wv;
  }
  float b = bm[c];
#pragma unroll
  for (int t = 0; t < 8; ++t) {
    int n = n0 + g * 8 + t;
    float v = acc[t] + b + feat[n * HID + c];
    feat[n * HID + c] = v;
    out[n * OUTW + outoff + c] = v;
  }
}

extern "C" void kernel_launch(void* const* d_in, const int* in_sizes, int n_in,
                              void* d_out, int out_size, void* d_ws, size_t ws_size,
                              hipStream_t stream) {
  const float* node_feat = (const float*)d_in[0];
  const float* edge_feat = (const float*)d_in[1];
  const int*   src       = (const int*)d_in[2];
  const int*   dst       = (const int*)d_in[3];
  const float* W_embed   = (const float*)d_in[4];
  const float* b_embed   = (const float*)d_in[5];
  const float* W_ni      = (const float*)d_in[6];
  const float* W_nj      = (const float*)d_in[7];
  const float* W_fij     = (const float*)d_in[8];
  const float* b_att     = (const float*)d_in[9];
  const float* attn      = (const float*)d_in[10];
  const float* W_node    = (const float*)d_in[11];
  const float* W_mlp     = (const float*)d_in[12];
  const float* b_mlp     = (const float*)d_in[13];
  float* out = (float*)d_out;

  // workspace layout
  float* ws   = (float*)d_ws;
  float* feat = ws;                                   // NN*HID f32
  u16*  fni   = (u16*)(feat + (size_t)NN * HID);      // NN*HD bf16
  u16*  fnj   = fni + (size_t)NN * HD;                // NN*HD bf16
  u16*  hn    = fnj + (size_t)NN * HD;                // NN*HD bf16
  u16*  efb   = hn + (size_t)NN * HD;                 // NE*HID bf16 (original order)
  u16*  Wt    = efb + (size_t)NE * HID;               // HD*HID bf16
  float* elog = (float*)(Wt + (size_t)HD * HID);      // NE*HEADS f32 (CSR order)
  int* counts = (int*)(elog + (size_t)NE * HEADS);    // NN
  int* rowptr = counts + NN;                          // NN+1
  int* cursor = rowptr + NN + 1;                      // NN
  int* eidx   = cursor + NN;                          // NE
  int* srcp   = eidx + NE;                            // NE
  int* dstp   = srcp + NE;                            // NE
  float* aggb = (float*)fni;  // overlay fni+fnj; safe: written after edgelogits.

  hipMemsetAsync(counts, 0, sizeof(int) * NN, stream);
  hipMemsetAsync(cursor, 0, sizeof(int) * NN, stream);

  k_embed<<<(NN * 64) / 256, 256, 0, stream>>>(node_feat, W_embed, b_embed, feat, out);
  k_count<<<NE / 256, 256, 0, stream>>>(dst, counts);
  k_scan<<<1, 1024, 0, stream>>>(counts, rowptr);
  k_scatter<<<NE / 256, 256, 0, stream>>>(dst, src, rowptr, cursor, eidx, srcp, dstp);
  k_convert<<<(NE * HID / 4) / 256, 256, 0, stream>>>(edge_feat, efb);

  for (int L = 0; L < 2; ++L) {
    const float* WniL = W_ni + (size_t)L * HID * HD;
    const float* WnjL = W_nj + (size_t)L * HID * HD;
    const float* WfL  = W_fij + (size_t)L * HID * HD;
    const float* WndL = W_node + (size_t)L * HID * HD;
    const float* battL = b_att + (size_t)L * HD;
    const float* attnL = attn + (size_t)L * HEADS * HID;
    const float* WmL  = W_mlp + (size_t)L * HD * HID;
    const float* bmL  = b_mlp + (size_t)L * HID;

    k_prepw<<<(HID * HD) / 256, 256, 0, stream>>>(WfL, Wt);
    k_nodeproj<<<NN / 16, 256, 0, stream>>>(feat, WniL, WnjL, WndL, battL, fni, fnj, hn);
    k_edgelogits<<<2500, 256, 0, stream>>>(efb, eidx, srcp, dstp, fni, fnj, Wt, attnL, elog);
    k_agg<<<(NN * 64) / 256, 256, 0, stream>>>(rowptr, srcp, elog, hn, aggb);
    k_mlp<<<NN / 32, 256, 0, stream>>>(aggb, WmL, bmL, feat, out, 80 + L * 64);
  }
}

// Round 7
// 568.749 us; speedup vs baseline: 1.0759x; 1.0759x over previous
//
#include <hip/hip_runtime.h>
#include <math.h>

#define NN 20000
#define NE 320000
#define IN_DIM 16
#define HID 64
#define HEADS 4
#define HD 256          // HEADS*HID
#define OUTW 208        // 16 + 3*64
#define NEG 0.2f

typedef unsigned short u16;
typedef unsigned int u32;
typedef __attribute__((ext_vector_type(8))) short bf16x8;   // MFMA A/B frag
typedef __attribute__((ext_vector_type(4))) float f32x4;    // MFMA C/D frag

__device__ __forceinline__ float b2f(u16 u) {
  union { u32 i; float f; } c; c.i = ((u32)u) << 16; return c.f;
}
__device__ __forceinline__ u16 f2b(float f) {
  union { float f; u32 i; } c; c.f = f;
  u32 r = (c.i + 0x7FFFu + ((c.i >> 16) & 1u)) >> 16;
  return (u16)r;
}

// ---------------- embed: feat = node_feat @ W_embed + b; also write out cols 0..79
__global__ void k_embed(const float* __restrict__ nf, const float* __restrict__ We,
                        const float* __restrict__ be, float* __restrict__ feat,
                        float* __restrict__ out) {
  int tid = blockIdx.x * blockDim.x + threadIdx.x;   // NN*64 threads
  int n = tid >> 6, c = tid & 63;
  if (n >= NN) return;
  float acc = be[c];
#pragma unroll
  for (int k = 0; k < IN_DIM; ++k)
    acc += nf[n * IN_DIM + k] * We[k * HID + c];
  feat[n * HID + c] = acc;
  out[n * OUTW + 16 + c] = acc;
  if (c < IN_DIM) out[n * OUTW + c] = nf[n * IN_DIM + c];
}

// ---------------- CSR build over dst
__global__ void k_count(const int* __restrict__ dst, int* __restrict__ counts) {
  int e = blockIdx.x * blockDim.x + threadIdx.x;
  if (e < NE) atomicAdd(&counts[dst[e]], 1);
}

// single block, 1024 threads, shuffle-based scan
__global__ void k_scan(const int* __restrict__ counts, int* __restrict__ rowptr) {
  __shared__ int wsum[16];
  __shared__ int tot;
  int lane = threadIdx.x & 63, wid = threadIdx.x >> 6;
  int running = 0;
  if (threadIdx.x == 0) rowptr[0] = 0;
  for (int base = 0; base < NN; base += 1024) {
    int i = base + threadIdx.x;
    int x = (i < NN) ? counts[i] : 0;
#pragma unroll
    for (int d = 1; d < 64; d <<= 1) {
      int t = __shfl_up(x, d);
      if (lane >= d) x += t;
    }
    if (lane == 63) wsum[wid] = x;
    __syncthreads();
    if (wid == 0) {
      int wv = (lane < 16) ? wsum[lane] : 0;
#pragma unroll
      for (int d = 1; d < 16; d <<= 1) {
        int t = __shfl_up(wv, d);
        if (lane >= d) wv += t;
      }
      if (lane < 16) wsum[lane] = wv;
      if (lane == 15) tot = wv;
    }
    __syncthreads();
    int wpre = (wid == 0) ? 0 : wsum[wid - 1];
    if (i < NN) rowptr[i + 1] = running + wpre + x;
    running += tot;
    __syncthreads();
  }
}

// scatter: eidx (CSR slot -> original edge), src/dst permuted into CSR order
__global__ void k_scatter(const int* __restrict__ dst, const int* __restrict__ src,
                          const int* __restrict__ rowptr, int* __restrict__ cursor,
                          int* __restrict__ eidx, int* __restrict__ srcp,
                          int* __restrict__ dstp) {
  int e = blockIdx.x * blockDim.x + threadIdx.x;
  if (e >= NE) return;
  int d = dst[e];
  int pos = rowptr[d] + atomicAdd(&cursor[d], 1);
  eidx[pos] = e;
  srcp[pos] = src[e];
  dstp[pos] = d;
}

// ---------------- coalesced f32 -> bf16 convert of edge_feat (original order)
__global__ void k_convert(const float* __restrict__ ef, u16* __restrict__ efb) {
  int t = blockIdx.x * blockDim.x + threadIdx.x;   // NE*HID/4 threads
  float4 v = *reinterpret_cast<const float4*>(&ef[(size_t)t * 4]);
  ushort4 o;
  o.x = f2b(v.x); o.y = f2b(v.y); o.z = f2b(v.z); o.w = f2b(v.w);
  *reinterpret_cast<ushort4*>(&efb[(size_t)t * 4]) = o;
}

// ---------------- transpose + bf16-convert W_fij: Wt[n][k] = Wf[k][n]
__global__ void k_prepw(const float* __restrict__ Wf, u16* __restrict__ Wt) {
  int tid = blockIdx.x * blockDim.x + threadIdx.x;   // HID*HD threads
  int n = tid >> 6, k = tid & 63;
  if (n >= HD) return;
  Wt[n * HID + k] = f2b(Wf[k * HD + n]);
}

// ---------------- node projections: fni (+b_att folded), fnj, hn -> bf16 (8/block)
__global__ __launch_bounds__(256) void k_nodeproj(
    const float* __restrict__ feat, const float* __restrict__ Wni,
    const float* __restrict__ Wnj, const float* __restrict__ Wnd,
    const float* __restrict__ batt, u16* __restrict__ fni,
    u16* __restrict__ fnj, u16* __restrict__ hn) {
  __shared__ float hs[8 * HID];
  int n0 = blockIdx.x * 8;
  int c = threadIdx.x;
  for (int i = threadIdx.x; i < 8 * HID; i += 256)
    hs[i] = feat[(size_t)(n0 + (i >> 6)) * HID + (i & 63)];
  __syncthreads();
  float aI[8] = {0}, aJ[8] = {0}, aN[8] = {0};
  for (int k = 0; k < HID; ++k) {
    float wi = Wni[k * HD + c], wj = Wnj[k * HD + c], wn = Wnd[k * HD + c];
#pragma unroll
    for (int t = 0; t < 8; ++t) {
      float x = hs[t * HID + k];
      aI[t] += x * wi; aJ[t] += x * wj; aN[t] += x * wn;
    }
  }
  float b = batt[c];
#pragma unroll
  for (int t = 0; t < 8; ++t) {
    int n = n0 + t;
    fni[(size_t)n * HD + c] = f2b(aI[t] + b);
    fnj[(size_t)n * HD + c] = f2b(aJ[t]);
    hn[(size_t)n * HD + c]  = f2b(aN[t]);
  }
}

// ---------------- edge logits via MFMA over CSR slots, 2-tile ILP
// elog head-major: elog[h*NE + slot]
__global__ __launch_bounds__(256) void k_edgelogits(
    const u16* __restrict__ efb, const int* __restrict__ eidx,
    const int* __restrict__ srcp, const int* __restrict__ dstp,
    const u16* __restrict__ fni, const u16* __restrict__ fnj,
    const u16* __restrict__ Wt, const float* __restrict__ attnL,
    float* __restrict__ elog) {
  __shared__ float gb[HEADS][16][68];   // per-wave slice, +4 pad
  int h = threadIdx.x >> 6;            // wave = head
  int l = threadIdx.x & 63;
  int q = l >> 4;                      // quad
  int n = l & 15;
  bf16x8 bfr[4][2];
#pragma unroll
  for (int nt = 0; nt < 4; ++nt)
#pragma unroll
    for (int kk = 0; kk < 2; ++kk)
      bfr[nt][kk] = *reinterpret_cast<const bf16x8*>(
          &Wt[(h * 64 + nt * 16 + n) * HID + kk * 32 + q * 8]);
  float at[4];
#pragma unroll
  for (int nt = 0; nt < 4; ++nt) at[nt] = attnL[h * 64 + nt * 16 + n];

  const int NT = NE / 16;  // 20000 tiles
  const int G = gridDim.x;
  for (int tile = blockIdx.x; tile < NT; tile += 2 * G) {
    int t1 = tile + G;
    // ---- issue ALL gathers for both tiles (2x memory-level parallelism)
    int i0 = tile * 16;
    int er0 = eidx[i0 + n];
    bf16x8 a00 = *reinterpret_cast<const bf16x8*>(&efb[(size_t)er0 * HID + q * 8]);
    bf16x8 a01 = *reinterpret_cast<const bf16x8*>(&efb[(size_t)er0 * HID + 32 + q * 8]);
    ushort4 av0[4], bv0[4];
#pragma unroll
    for (int p = 0; p < 4; ++p) {
      int i = i0 + p * 4 + q;
      int s = srcp[i], d = dstp[i];
      av0[p] = *reinterpret_cast<const ushort4*>(&fni[(size_t)s * HD + h * 64 + 4 * n]);
      bv0[p] = *reinterpret_cast<const ushort4*>(&fnj[(size_t)d * HD + h * 64 + 4 * n]);
    }
    int i1 = 0;
    bf16x8 a10 = {}, a11 = {};
    ushort4 av1[4], bv1[4];
    bool has1 = (t1 < NT);
    if (has1) {
      i1 = t1 * 16;
      int er1 = eidx[i1 + n];
      a10 = *reinterpret_cast<const bf16x8*>(&efb[(size_t)er1 * HID + q * 8]);
      a11 = *reinterpret_cast<const bf16x8*>(&efb[(size_t)er1 * HID + 32 + q * 8]);
#pragma unroll
      for (int p = 0; p < 4; ++p) {
        int i = i1 + p * 4 + q;
        int s = srcp[i], d = dstp[i];
        av1[p] = *reinterpret_cast<const ushort4*>(&fni[(size_t)s * HD + h * 64 + 4 * n]);
        bv1[p] = *reinterpret_cast<const ushort4*>(&fnj[(size_t)d * HD + h * 64 + 4 * n]);
      }
    }
    // ---- tile 0: commit to wave-private LDS, MFMA, epilogue
#pragma unroll
    for (int p = 0; p < 4; ++p) {
      float4 g;
      g.x = b2f(av0[p].x) + b2f(bv0[p].x);
      g.y = b2f(av0[p].y) + b2f(bv0[p].y);
      g.z = b2f(av0[p].z) + b2f(bv0[p].z);
      g.w = b2f(av0[p].w) + b2f(bv0[p].w);
      *reinterpret_cast<float4*>(&gb[h][p * 4 + q][4 * n]) = g;
    }
    float sumr[4] = {0.f, 0.f, 0.f, 0.f};
#pragma unroll
    for (int nt = 0; nt < 4; ++nt) {
      f32x4 acc = {0.f, 0.f, 0.f, 0.f};
      acc = __builtin_amdgcn_mfma_f32_16x16x32_bf16(a00, bfr[nt][0], acc, 0, 0, 0);
      acc = __builtin_amdgcn_mfma_f32_16x16x32_bf16(a01, bfr[nt][1], acc, 0, 0, 0);
#pragma unroll
      for (int r = 0; r < 4; ++r) {
        float v = acc[r] + gb[h][q * 4 + r][nt * 16 + n];
        v = v > 0.f ? v : NEG * v;
        sumr[r] += v * at[nt];
      }
    }
#pragma unroll
    for (int r = 0; r < 4; ++r) {
      float v = sumr[r];
      v += __shfl_xor(v, 1);
      v += __shfl_xor(v, 2);
      v += __shfl_xor(v, 4);
      v += __shfl_xor(v, 8);
      sumr[r] = v;
    }
    if (n == 0) {
#pragma unroll
      for (int r = 0; r < 4; ++r)
        elog[(size_t)h * NE + i0 + q * 4 + r] = sumr[r];
    }
    // ---- tile 1 (same LDS slice, wave-private reuse)
    if (has1) {
#pragma unroll
      for (int p = 0; p < 4; ++p) {
        float4 g;
        g.x = b2f(av1[p].x) + b2f(bv1[p].x);
        g.y = b2f(av1[p].y) + b2f(bv1[p].y);
        g.z = b2f(av1[p].z) + b2f(bv1[p].z);
        g.w = b2f(av1[p].w) + b2f(bv1[p].w);
        *reinterpret_cast<float4*>(&gb[h][p * 4 + q][4 * n]) = g;
      }
      float sum1[4] = {0.f, 0.f, 0.f, 0.f};
#pragma unroll
      for (int nt = 0; nt < 4; ++nt) {
        f32x4 acc = {0.f, 0.f, 0.f, 0.f};
        acc = __builtin_amdgcn_mfma_f32_16x16x32_bf16(a10, bfr[nt][0], acc, 0, 0, 0);
        acc = __builtin_amdgcn_mfma_f32_16x16x32_bf16(a11, bfr[nt][1], acc, 0, 0, 0);
#pragma unroll
        for (int r = 0; r < 4; ++r) {
          float v = acc[r] + gb[h][q * 4 + r][nt * 16 + n];
          v = v > 0.f ? v : NEG * v;
          sum1[r] += v * at[nt];
        }
      }
#pragma unroll
      for (int r = 0; r < 4; ++r) {
        float v = sum1[r];
        v += __shfl_xor(v, 1);
        v += __shfl_xor(v, 2);
        v += __shfl_xor(v, 4);
        v += __shfl_xor(v, 8);
        sum1[r] = v;
      }
      if (n == 0) {
#pragma unroll
        for (int r = 0; r < 4; ++r)
          elog[(size_t)h * NE + i1 + q * 4 + r] = sum1[r];
      }
    }
  }
}

// ---------------- per-(node,head) softmax stats (elog head-major, coalesced)
__global__ void k_mz(const int* __restrict__ rowptr, const float* __restrict__ elog,
                     float* __restrict__ mz) {
  int t = blockIdx.x * blockDim.x + threadIdx.x;
  if (t >= NN * HEADS) return;
  int h = t / NN, n = t - h * NN;    // adjacent threads: consecutive n, same h
  int s0 = rowptr[n], s1 = rowptr[n + 1];
  const float* er = elog + (size_t)h * NE;
  float m = -1e30f;
  for (int i = s0; i < s1; ++i) m = fmaxf(m, er[i]);
  float z = 0.f;
  for (int i = s0; i < s1; ++i) z += __expf(er[i] - m);
  mz[n * 8 + h] = m;
  mz[n * 8 + 4 + h] = (z > 0.f) ? 1.0f / z : 0.f;
}

// ---------------- aggregation: one wave per node, unroll x8, softmax on the fly
__global__ __launch_bounds__(256) void k_agg(
    const int* __restrict__ rowptr, const int* __restrict__ srcp,
    const float* __restrict__ elog, const float* __restrict__ mz,
    const u16* __restrict__ hn, float* __restrict__ agg) {
  int n = (blockIdx.x * blockDim.x + threadIdx.x) >> 6;
  int j = threadIdx.x & 63;
  if (n >= NN) return;
  int s0 = rowptr[n], s1 = rowptr[n + 1];
  int h = j >> 4;
  float m = mz[n * 8 + h], invz = mz[n * 8 + 4 + h];
  const float* er = elog + (size_t)h * NE;
  float4 ac[8];
#pragma unroll
  for (int t = 0; t < 8; ++t) ac[t] = make_float4(0, 0, 0, 0);
  int i = s0;
  for (; i + 8 <= s1; i += 8) {
    int sv[8]; float wv[8]; ushort4 vv[8];
#pragma unroll
    for (int t = 0; t < 8; ++t) sv[t] = srcp[i + t];
#pragma unroll
    for (int t = 0; t < 8; ++t) wv[t] = __expf(er[i + t] - m) * invz;
#pragma unroll
    for (int t = 0; t < 8; ++t)
      vv[t] = *reinterpret_cast<const ushort4*>(&hn[(size_t)sv[t] * HD + 4 * j]);
#pragma unroll
    for (int t = 0; t < 8; ++t) {
      ac[t].x += b2f(vv[t].x) * wv[t]; ac[t].y += b2f(vv[t].y) * wv[t];
      ac[t].z += b2f(vv[t].z) * wv[t]; ac[t].w += b2f(vv[t].w) * wv[t];
    }
  }
  for (; i < s1; ++i) {
    int s = srcp[i];
    float w = __expf(er[i] - m) * invz;
    ushort4 v = *reinterpret_cast<const ushort4*>(&hn[(size_t)s * HD + 4 * j]);
    ac[0].x += b2f(v.x) * w; ac[0].y += b2f(v.y) * w;
    ac[0].z += b2f(v.z) * w; ac[0].w += b2f(v.w) * w;
  }
  float4 acc;
  acc.x = ((ac[0].x + ac[1].x) + (ac[2].x + ac[3].x)) + ((ac[4].x + ac[5].x) + (ac[6].x + ac[7].x));
  acc.y = ((ac[0].y + ac[1].y) + (ac[2].y + ac[3].y)) + ((ac[4].y + ac[5].y) + (ac[6].y + ac[7].y));
  acc.z = ((ac[0].z + ac[1].z) + (ac[2].z + ac[3].z)) + ((ac[4].z + ac[5].z) + (ac[6].z + ac[7].z));
  acc.w = ((ac[0].w + ac[1].w) + (ac[2].w + ac[3].w)) + ((ac[4].w + ac[5].w) + (ac[6].w + ac[7].w));
  *reinterpret_cast<float4*>(&agg[(size_t)n * HD + 4 * j]) = acc;
}

// ---------------- MLP + residual: feat = agg @ W_mlp + b + feat; write out slice
__global__ __launch_bounds__(256) void k_mlp(
    const float* __restrict__ agg, const float* __restrict__ Wm,
    const float* __restrict__ bm, float* __restrict__ feat,
    float* __restrict__ out, int outoff) {
  __shared__ float as_[32 * HD];
  int n0 = blockIdx.x * 32;
  for (int i = threadIdx.x; i < 32 * HD; i += 256) as_[i] = agg[(size_t)n0 * HD + i];
  __syncthreads();
  int c = threadIdx.x & 63;
  int g = threadIdx.x >> 6;
  float acc[8] = {0};
  for (int k = 0; k < HD; ++k) {
    float wv = Wm[k * HID + c];
#pragma unroll
    for (int t = 0; t < 8; ++t)
      acc[t] += as_[(g * 8 + t) * HD + k] * wv;
  }
  float b = bm[c];
#pragma unroll
  for (int t = 0; t < 8; ++t) {
    int n = n0 + g * 8 + t;
    float v = acc[t] + b + feat[n * HID + c];
    feat[n * HID + c] = v;
    out[n * OUTW + outoff + c] = v;
  }
}

extern "C" void kernel_launch(void* const* d_in, const int* in_sizes, int n_in,
                              void* d_out, int out_size, void* d_ws, size_t ws_size,
                              hipStream_t stream) {
  const float* node_feat = (const float*)d_in[0];
  const float* edge_feat = (const float*)d_in[1];
  const int*   src       = (const int*)d_in[2];
  const int*   dst       = (const int*)d_in[3];
  const float* W_embed   = (const float*)d_in[4];
  const float* b_embed   = (const float*)d_in[5];
  const float* W_ni      = (const float*)d_in[6];
  const float* W_nj      = (const float*)d_in[7];
  const float* W_fij     = (const float*)d_in[8];
  const float* b_att     = (const float*)d_in[9];
  const float* attn      = (const float*)d_in[10];
  const float* W_node    = (const float*)d_in[11];
  const float* W_mlp     = (const float*)d_in[12];
  const float* b_mlp     = (const float*)d_in[13];
  float* out = (float*)d_out;

  // workspace layout
  float* ws   = (float*)d_ws;
  float* feat = ws;                                   // NN*HID f32
  u16*  fni   = (u16*)(feat + (size_t)NN * HID);      // NN*HD bf16
  u16*  fnj   = fni + (size_t)NN * HD;                // NN*HD bf16
  u16*  hn    = fnj + (size_t)NN * HD;                // NN*HD bf16
  u16*  efb   = hn + (size_t)NN * HD;                 // NE*HID bf16 (original order)
  u16*  Wt    = efb + (size_t)NE * HID;               // HD*HID bf16
  float* elog = (float*)(Wt + (size_t)HD * HID);      // HEADS*NE f32 (head-major)
  float* mz   = elog + (size_t)NE * HEADS;            // NN*8 f32
  int* counts = (int*)(mz + (size_t)NN * 8);          // NN
  int* rowptr = counts + NN;                          // NN+1
  int* cursor = rowptr + NN + 1;                      // NN
  int* eidx   = cursor + NN;                          // NE
  int* srcp   = eidx + NE;                            // NE
  int* dstp   = srcp + NE;                            // NE
  float* aggb = (float*)fni;  // overlay fni+fnj; safe: written after edgelogits.

  hipMemsetAsync(counts, 0, sizeof(int) * NN, stream);
  hipMemsetAsync(cursor, 0, sizeof(int) * NN, stream);

  k_embed<<<(NN * 64) / 256, 256, 0, stream>>>(node_feat, W_embed, b_embed, feat, out);
  k_count<<<NE / 256, 256, 0, stream>>>(dst, counts);
  k_scan<<<1, 1024, 0, stream>>>(counts, rowptr);
  k_scatter<<<NE / 256, 256, 0, stream>>>(dst, src, rowptr, cursor, eidx, srcp, dstp);
  k_convert<<<(NE * HID / 4) / 256, 256, 0, stream>>>(edge_feat, efb);

  for (int L = 0; L < 2; ++L) {
    const float* WniL = W_ni + (size_t)L * HID * HD;
    const float* WnjL = W_nj + (size_t)L * HID * HD;
    const float* WfL  = W_fij + (size_t)L * HID * HD;
    const float* WndL = W_node + (size_t)L * HID * HD;
    const float* battL = b_att + (size_t)L * HD;
    const float* attnL = attn + (size_t)L * HEADS * HID;
    const float* WmL  = W_mlp + (size_t)L * HD * HID;
    const float* bmL  = b_mlp + (size_t)L * HID;

    k_prepw<<<(HID * HD) / 256, 256, 0, stream>>>(WfL, Wt);
    k_nodeproj<<<NN / 8, 256, 0, stream>>>(feat, WniL, WnjL, WndL, battL, fni, fnj, hn);
    k_edgelogits<<<2500, 256, 0, stream>>>(efb, eidx, srcp, dstp, fni, fnj, Wt, attnL, elog);
    k_mz<<<(NN * HEADS + 255) / 256, 256, 0, stream>>>(rowptr, elog, mz);
    k_agg<<<(NN * 64) / 256, 256, 0, stream>>>(rowptr, srcp, elog, mz, hn, aggb);
    k_mlp<<<NN / 32, 256, 0, stream>>>(aggb, WmL, bmL, feat, out, 80 + L * 64);
  }
}